// Round 1
// baseline (1126.154 us; speedup 1.0000x reference)
//
#include <hip/hip_runtime.h>
#include <math.h>

#define S_LEN 4096
#define D_DIM 64
#define H_NUM 16
#define WIN   256
#define TQ    32       // 32 q-rows/block: same NCH=9 chunk count covers the 544-key union,
                       // halving staging+barrier overhead per output row
#define NCH   9        // 9 chunks x 64 keys = 576 >= 543+1 band union for 32 rows
#define KSTR  72       // u16 stride of K-chunk / Q rows (pad breaks bank stride)
#define PBSTR 584      // u16 stride of pbf rows (576 keys + 8 pad, 16B-aligned)

typedef __attribute__((ext_vector_type(8))) short          bf16x8;
typedef __attribute__((ext_vector_type(4))) float          f32x4;
typedef __attribute__((ext_vector_type(8))) unsigned short u16x8;
typedef __attribute__((ext_vector_type(4))) unsigned short u16x4;

static __device__ __forceinline__ unsigned short f2bf(float x) {
    unsigned int u = __float_as_uint(x);
    u = (u + 0x7FFFu + ((u >> 16) & 1u)) >> 16;   // RNE
    return (unsigned short)u;
}
static __device__ __forceinline__ float bf2f(unsigned short h) {
    return __uint_as_float(((unsigned int)h) << 16);
}

// LDS: pbf 37376 + kvb 9216 + qbf 4608 + red 512 + linv 128 = 51840 B -> 3 blocks/CU.
// Trade: 5->3 blocks/CU occupancy vs 2x fewer barriers per output + reg-prefetched staging.
__global__ __launch_bounds__(256) void swa_kernel(
    const float* __restrict__ Q,
    const float* __restrict__ K,
    const float* __restrict__ V,
    float* __restrict__ out,
    float* __restrict__ attn)
{
    const int tid = threadIdx.x;
    const int q0  = blockIdx.x * TQ;
    const int h   = blockIdx.y;

    const float* __restrict__ Qh = Q + (size_t)h * S_LEN * D_DIM;
    const float* __restrict__ Kh = K + (size_t)h * S_LEN * D_DIM;
    const float* __restrict__ Vh = V + (size_t)h * S_LEN * D_DIM;

    __shared__ unsigned short qbf[TQ * KSTR];
    __shared__ unsigned short kvb[64 * KSTR];     // K chunk (stride 72) / Vt (stride 64)
    __shared__ unsigned short pbf[TQ * PBSTR];    // unnormalized exp(scores), bf16
    __shared__ float red[4 * TQ];
    __shared__ float linv[TQ];

    const int k0   = max(q0 - WIN, 0);
    const int lane = tid & 63;
    const int wv   = tid >> 6;      // wave id: key-tile (pass1) / d-tile (PV)
    const int quad = lane >> 4;     // MFMA k-group / CD row-group
    const int n16  = lane & 15;     // MFMA m/n index

    // staging assignment shared by K and V chunks: thread -> (key, 16 consecutive d)
    const int skey = tid >> 2, sd0 = (tid & 3) * 16;

    // ---- prefetch K chunk 0 into registers (latency hidden under Q staging) ----
    float4 kx0, kx1, kx2, kx3;
    {
        const int kg = min(k0 + skey, S_LEN - 1);
        const float4* s4 = (const float4*)(Kh + (size_t)kg * D_DIM + sd0);
        kx0 = s4[0]; kx1 = s4[1]; kx2 = s4[2]; kx3 = s4[3];
    }

    // ---- stage Q tile as bf16 ----
    {
        const int row = tid >> 3, c8 = (tid & 7) * 8;
        const float4 v0 = *(const float4*)(Qh + (size_t)(q0 + row) * D_DIM + c8);
        const float4 v1 = *(const float4*)(Qh + (size_t)(q0 + row) * D_DIM + c8 + 4);
        u16x8 p;
        p[0]=f2bf(v0.x); p[1]=f2bf(v0.y); p[2]=f2bf(v0.z); p[3]=f2bf(v0.w);
        p[4]=f2bf(v1.x); p[5]=f2bf(v1.y); p[6]=f2bf(v1.z); p[7]=f2bf(v1.w);
        *(u16x8*)&qbf[row * KSTR + c8] = p;
    }
    __syncthreads();

    // Q A-fragments for both q-tiles: A[m=n16][k=quad*8+j], k halves [0,32) and [32,64)
    bf16x8 aqf[2][2];
    #pragma unroll
    for (int qt = 0; qt < 2; ++qt) {
        aqf[qt][0] = *(const bf16x8*)&qbf[(qt * 16 + n16) * KSTR + quad * 8];
        aqf[qt][1] = *(const bf16x8*)&qbf[(qt * 16 + n16) * KSTR + 32 + quad * 8];
    }

    // ---------------- Pass 1: QK^T via MFMA, fused exp + pbf + row-sums ----------------
    float psum[8] = {0.f,0.f,0.f,0.f,0.f,0.f,0.f,0.f};   // [qt*4+r]
    #pragma unroll
    for (int c = 0; c < NCH; ++c) {
        const int kb = k0 + c * 64;
        {   // convert prefetched regs -> bf16 K chunk, row-major, stride 72
            u16x8 p0, p1;
            p0[0]=f2bf(kx0.x); p0[1]=f2bf(kx0.y); p0[2]=f2bf(kx0.z); p0[3]=f2bf(kx0.w);
            p0[4]=f2bf(kx1.x); p0[5]=f2bf(kx1.y); p0[6]=f2bf(kx1.z); p0[7]=f2bf(kx1.w);
            p1[0]=f2bf(kx2.x); p1[1]=f2bf(kx2.y); p1[2]=f2bf(kx2.z); p1[3]=f2bf(kx2.w);
            p1[4]=f2bf(kx3.x); p1[5]=f2bf(kx3.y); p1[6]=f2bf(kx3.z); p1[7]=f2bf(kx3.w);
            *(u16x8*)&kvb[skey * KSTR + sd0]     = p0;
            *(u16x8*)&kvb[skey * KSTR + sd0 + 8] = p1;
        }
        __syncthreads();

        // issue next chunk's K loads NOW; latency hides under MFMA+exp below
        if (c + 1 < NCH) {
            const int kg = min(kb + 64 + skey, S_LEN - 1);
            const float4* s4 = (const float4*)(Kh + (size_t)kg * D_DIM + sd0);
            kx0 = s4[0]; kx1 = s4[1]; kx2 = s4[2]; kx3 = s4[3];
        }

        // B[k=d][n=key]: lane reads K[key=wv*16+n16][d=quad*8+j] (contiguous)
        const bf16x8 b0 = *(const bf16x8*)&kvb[(wv * 16 + n16) * KSTR + quad * 8];
        const bf16x8 b1 = *(const bf16x8*)&kvb[(wv * 16 + n16) * KSTR + 32 + quad * 8];
        const int key_abs = kb + wv * 16 + n16;
        #pragma unroll
        for (int qt = 0; qt < 2; ++qt) {
            f32x4 acc = {0.f, 0.f, 0.f, 0.f};
            acc = __builtin_amdgcn_mfma_f32_16x16x32_bf16(aqf[qt][0], b0, acc, 0, 0, 0);
            acc = __builtin_amdgcn_mfma_f32_16x16x32_bf16(aqf[qt][1], b1, acc, 0, 0, 0);

            // D: col(lane&15)=key-in-tile, row=quad*4+reg=q row. No max-subtraction:
            // |scores| <~ 8 so exp() is safe in fp32 (ref's softmax shift cancels).
            #pragma unroll
            for (int r = 0; r < 4; ++r) {
                const int qrow  = qt * 16 + quad * 4 + r;
                const int q_abs = q0 + qrow;
                const bool in   = (key_abs < S_LEN) &&
                                  (key_abs >= q_abs - WIN) && (key_abs <= q_abs + WIN);
                const float e = in ? __expf(acc[r] * 0.125f) : 0.f;
                pbf[qrow * PBSTR + c * 64 + wv * 16 + n16] = f2bf(e);
                psum[qt * 4 + r] += e;
            }
        }
        __syncthreads();
    }

    // ---- prefetch V chunk 0 (hides under row-sum reduction) ----
    float4 vx0, vx1, vx2, vx3;
    {
        const int kg = min(k0 + skey, S_LEN - 1);
        const float4* s4 = (const float4*)(Vh + (size_t)kg * D_DIM + sd0);
        vx0 = s4[0]; vx1 = s4[1]; vx2 = s4[2]; vx3 = s4[3];
    }

    // ---- row sums -> linv ----
    #pragma unroll
    for (int i = 0; i < 8; ++i) {
        float s = psum[i];
        s += __shfl_down(s, 8, 16);
        s += __shfl_down(s, 4, 16);
        s += __shfl_down(s, 2, 16);
        s += __shfl_down(s, 1, 16);
        if (n16 == 0) red[wv * TQ + (i >> 2) * 16 + quad * 4 + (i & 3)] = s;
    }
    __syncthreads();
    if (tid < TQ)
        linv[tid] = 1.f / (red[tid] + red[TQ + tid] + red[2 * TQ + tid] + red[3 * TQ + tid]);
    __syncthreads();

    // ---------------- Pass 2: PV via MFMA (V transposed + XOR-swizzled in LDS) ----------------
    f32x4 oacc0 = {0.f, 0.f, 0.f, 0.f};
    f32x4 oacc1 = {0.f, 0.f, 0.f, 0.f};
    const int dd = wv * 16 + n16;                       // this lane's output d
    const int sd = ((dd >> 4) + (dd & 7)) & 7;          // read-side swizzle
    #pragma unroll
    for (int c = 0; c < NCH; ++c) {
        {   // stage V chunk transposed from regs: Vt[d][key^8*s(d)] bf16, stride 64
            const float vals[16] = {vx0.x,vx0.y,vx0.z,vx0.w, vx1.x,vx1.y,vx1.z,vx1.w,
                                    vx2.x,vx2.y,vx2.z,vx2.w, vx3.x,vx3.y,vx3.z,vx3.w};
            #pragma unroll
            for (int jj = 0; jj < 16; ++jj) {
                const int d  = sd0 + jj;
                const int sw = ((d >> 4) + (d & 7)) & 7;
                kvb[d * 64 + (skey ^ (sw * 8))] = f2bf(vals[jj]);
            }
        }
        __syncthreads();

        // issue next chunk's V loads; latency hides under PV MFMAs below
        if (c + 1 < NCH) {
            const int kg = min(k0 + (c + 1) * 64 + skey, S_LEN - 1);
            const float4* s4 = (const float4*)(Vh + (size_t)kg * D_DIM + sd0);
            vx0 = s4[0]; vx1 = s4[1]; vx2 = s4[2]; vx3 = s4[3];
        }

        // B = Vt[k=key][n=d] shared across both q-tiles; A = P[m=q][k=key] from pbf
        const bf16x8 vb0 = *(const bf16x8*)&kvb[dd * 64 + 8 * (quad ^ sd)];
        const bf16x8 vb1 = *(const bf16x8*)&kvb[dd * 64 + 8 * ((4 + quad) ^ sd)];
        const bf16x8 pa00 = *(const bf16x8*)&pbf[n16 * PBSTR + c * 64 + quad * 8];
        const bf16x8 pa01 = *(const bf16x8*)&pbf[n16 * PBSTR + c * 64 + 32 + quad * 8];
        const bf16x8 pa10 = *(const bf16x8*)&pbf[(16 + n16) * PBSTR + c * 64 + quad * 8];
        const bf16x8 pa11 = *(const bf16x8*)&pbf[(16 + n16) * PBSTR + c * 64 + 32 + quad * 8];
        oacc0 = __builtin_amdgcn_mfma_f32_16x16x32_bf16(pa00, vb0, oacc0, 0, 0, 0);
        oacc0 = __builtin_amdgcn_mfma_f32_16x16x32_bf16(pa01, vb1, oacc0, 0, 0, 0);
        oacc1 = __builtin_amdgcn_mfma_f32_16x16x32_bf16(pa10, vb0, oacc1, 0, 0, 0);
        oacc1 = __builtin_amdgcn_mfma_f32_16x16x32_bf16(pa11, vb1, oacc1, 0, 0, 0);
        __syncthreads();
    }
    #pragma unroll
    for (int r = 0; r < 4; ++r) {
        const int qr = quad * 4 + r;
        out[((size_t)h * S_LEN + q0 + qr) * D_DIM + dd]      = oacc0[r] * linv[qr];
        out[((size_t)h * S_LEN + q0 + 16 + qr) * D_DIM + dd] = oacc1[r] * linv[16 + qr];
    }

    // ---------------- attn rows: full 4096-wide, zeros outside band (LAST; nontemporal) ----------------
    for (int qq = 0; qq < TQ; ++qq) {
        const int qa  = q0 + qq;
        const int b0q = max(qa - WIN, 0);
        const int b1q = min(qa + WIN, S_LEN - 1);
        const float qi = linv[qq];
        f32x4* arow = (f32x4*)(attn + ((size_t)h * S_LEN + qa) * S_LEN);
        const unsigned short* prow = &pbf[qq * PBSTR];
        for (int j4 = tid; j4 < S_LEN / 4; j4 += 256) {
            const int j = j4 * 4;
            f32x4 w = {0.f, 0.f, 0.f, 0.f};
            if (j >= b0q && j + 3 <= b1q) {
                const u16x4 p = *(const u16x4*)&prow[j - k0];
                w[0] = bf2f(p.x) * qi; w[1] = bf2f(p.y) * qi;
                w[2] = bf2f(p.z) * qi; w[3] = bf2f(p.w) * qi;
            } else if (j + 3 >= b0q && j <= b1q) {
                #pragma unroll
                for (int e = 0; e < 4; ++e) {
                    const int jj = j + e;
                    if (jj >= b0q && jj <= b1q) w[e] = bf2f(prow[jj - k0]) * qi;
                }
            }
            __builtin_nontemporal_store(w, &arow[j4]);
        }
    }
}

extern "C" void kernel_launch(void* const* d_in, const int* in_sizes, int n_in,
                              void* d_out, int out_size, void* d_ws, size_t ws_size,
                              hipStream_t stream) {
    const float* Q = (const float*)d_in[0];
    const float* K = (const float*)d_in[1];
    const float* V = (const float*)d_in[2];
    float* out  = (float*)d_out;
    float* attn = out + (size_t)H_NUM * S_LEN * D_DIM;

    dim3 grid(S_LEN / TQ, H_NUM);
    swa_kernel<<<grid, 256, 0, stream>>>(Q, K, V, out, attn);
}

// Round 2
// 1099.930 us; speedup vs baseline: 1.0238x; 1.0238x over previous
//
#include <hip/hip_runtime.h>
#include <math.h>

#define S_LEN 4096
#define D_DIM 64
#define H_NUM 16
#define WIN   256
#define TQ    32       // 32 q-rows/block; NCH=9 chunks cover the 544-key band union
#define NCH   9        // 9 chunks x 64 keys = 576 >= band union for 32 rows
#define KSTR  72       // u16 stride of K-chunk / Q rows (pad breaks bank stride)
#define PBSTR 584      // u16 stride of pbf rows (576 keys + 8 pad, 16B-aligned)

typedef __attribute__((ext_vector_type(8))) short          bf16x8;
typedef __attribute__((ext_vector_type(4))) float          f32x4;
typedef __attribute__((ext_vector_type(8))) unsigned short u16x8;
typedef __attribute__((ext_vector_type(4))) unsigned short u16x4;

static __device__ __forceinline__ unsigned short f2bf(float x) {
    unsigned int u = __float_as_uint(x);
    u = (u + 0x7FFFu + ((u >> 16) & 1u)) >> 16;   // RNE
    return (unsigned short)u;
}
static __device__ __forceinline__ float bf2f(unsigned short h) {
    return __uint_as_float(((unsigned int)h) << 16);
}

// LDS: pbf 37376 + kvb 9216 + qbf 4608 + red 512 + linv 128 = 51840 B -> 3 blocks/CU.
// Zero-region attn writes (86% of write bytes) are interleaved into the 18 chunk
// phases so their HBM time overlaps the latency-bound compute instead of being a
// serial tail; only the 576-wide band span is written in the epilogue.
__global__ __launch_bounds__(256) void swa_kernel(
    const float* __restrict__ Q,
    const float* __restrict__ K,
    const float* __restrict__ V,
    float* __restrict__ out,
    float* __restrict__ attn)
{
    const int tid = threadIdx.x;
    const int q0  = blockIdx.x * TQ;
    const int h   = blockIdx.y;

    const float* __restrict__ Qh = Q + (size_t)h * S_LEN * D_DIM;
    const float* __restrict__ Kh = K + (size_t)h * S_LEN * D_DIM;
    const float* __restrict__ Vh = V + (size_t)h * S_LEN * D_DIM;

    __shared__ unsigned short qbf[TQ * KSTR];
    __shared__ unsigned short kvb[64 * KSTR];     // K chunk (stride 72) / Vt (stride 64)
    __shared__ unsigned short pbf[TQ * PBSTR];    // unnormalized exp(scores), bf16
    __shared__ float red[4 * TQ];
    __shared__ float linv[TQ];

    const int k0   = max(q0 - WIN, 0);
    const int lane = tid & 63;
    const int wv   = tid >> 6;      // wave id: key-tile (pass1) / d-tile (PV)
    const int quad = lane >> 4;     // MFMA k-group / CD row-group
    const int n16  = lane & 15;     // MFMA m/n index

    // zero-region geometry (per attn row): left [0,k0), span [k0,k0+576), right [k0+576,4096)
    const int l4  = k0 >> 2;                         // left width in f32x4
    const int e4  = l4 + 144;                        // span end in f32x4 units
    const int r4  = (e4 < 1024) ? (1024 - e4) : 0;   // right width
    const int zp4 = l4 + r4;                         // zero f32x4 per row
    const f32x4 zero4 = {0.f, 0.f, 0.f, 0.f};

    // ZEROS(p): write the dependency-free out-of-band zeros for rows 2p, 2p+1.
    // Issued right after a phase-start barrier -> whole phase to retire.
#define ZEROS(p)                                                                 \
    if ((p) < 16) {                                                              \
        _Pragma("unroll")                                                        \
        for (int rr = 0; rr < 2; ++rr) {                                         \
            const int qq = 2 * (p) + rr;                                         \
            f32x4* arow = (f32x4*)(attn + ((size_t)h * S_LEN + q0 + qq) * S_LEN);\
            _Pragma("unroll")                                                    \
            for (int it = 0; it < 4; ++it) {                                     \
                const int c4 = tid + it * 256;                                   \
                if (c4 < zp4) {                                                  \
                    const int col4 = (c4 < l4) ? c4 : (c4 - l4 + e4);            \
                    __builtin_nontemporal_store(zero4, &arow[col4]);             \
                }                                                                \
            }                                                                    \
        }                                                                        \
    }

    // staging assignment shared by K and V chunks: thread -> (key, 16 consecutive d)
    const int skey = tid >> 2, sd0 = (tid & 3) * 16;

    // ---- prefetch K chunk 0 into registers (latency hidden under Q staging) ----
    float4 kx0, kx1, kx2, kx3;
    {
        const int kg = min(k0 + skey, S_LEN - 1);
        const float4* s4 = (const float4*)(Kh + (size_t)kg * D_DIM + sd0);
        kx0 = s4[0]; kx1 = s4[1]; kx2 = s4[2]; kx3 = s4[3];
    }

    // ---- stage Q tile as bf16 ----
    {
        const int row = tid >> 3, c8 = (tid & 7) * 8;
        const float4 v0 = *(const float4*)(Qh + (size_t)(q0 + row) * D_DIM + c8);
        const float4 v1 = *(const float4*)(Qh + (size_t)(q0 + row) * D_DIM + c8 + 4);
        u16x8 p;
        p[0]=f2bf(v0.x); p[1]=f2bf(v0.y); p[2]=f2bf(v0.z); p[3]=f2bf(v0.w);
        p[4]=f2bf(v1.x); p[5]=f2bf(v1.y); p[6]=f2bf(v1.z); p[7]=f2bf(v1.w);
        *(u16x8*)&qbf[row * KSTR + c8] = p;
    }
    __syncthreads();

    // Q A-fragments for both q-tiles: A[m=n16][k=quad*8+j], k halves [0,32) and [32,64)
    bf16x8 aqf[2][2];
    #pragma unroll
    for (int qt = 0; qt < 2; ++qt) {
        aqf[qt][0] = *(const bf16x8*)&qbf[(qt * 16 + n16) * KSTR + quad * 8];
        aqf[qt][1] = *(const bf16x8*)&qbf[(qt * 16 + n16) * KSTR + 32 + quad * 8];
    }

    // ---------------- Pass 1: QK^T via MFMA, fused exp + pbf + row-sums ----------------
    float psum[8] = {0.f,0.f,0.f,0.f,0.f,0.f,0.f,0.f};   // [qt*4+r]
    #pragma unroll
    for (int c = 0; c < NCH; ++c) {
        const int kb = k0 + c * 64;
        {   // convert prefetched regs -> bf16 K chunk, row-major, stride 72
            u16x8 p0, p1;
            p0[0]=f2bf(kx0.x); p0[1]=f2bf(kx0.y); p0[2]=f2bf(kx0.z); p0[3]=f2bf(kx0.w);
            p0[4]=f2bf(kx1.x); p0[5]=f2bf(kx1.y); p0[6]=f2bf(kx1.z); p0[7]=f2bf(kx1.w);
            p1[0]=f2bf(kx2.x); p1[1]=f2bf(kx2.y); p1[2]=f2bf(kx2.z); p1[3]=f2bf(kx2.w);
            p1[4]=f2bf(kx3.x); p1[5]=f2bf(kx3.y); p1[6]=f2bf(kx3.z); p1[7]=f2bf(kx3.w);
            *(u16x8*)&kvb[skey * KSTR + sd0]     = p0;
            *(u16x8*)&kvb[skey * KSTR + sd0 + 8] = p1;
        }
        __syncthreads();

        ZEROS(c);   // overlap out-of-band attn zero-writes with this phase

        // issue next chunk's K loads NOW; latency hides under MFMA+exp below
        if (c + 1 < NCH) {
            const int kg = min(kb + 64 + skey, S_LEN - 1);
            const float4* s4 = (const float4*)(Kh + (size_t)kg * D_DIM + sd0);
            kx0 = s4[0]; kx1 = s4[1]; kx2 = s4[2]; kx3 = s4[3];
        }

        // B[k=d][n=key]: lane reads K[key=wv*16+n16][d=quad*8+j] (contiguous)
        const bf16x8 b0 = *(const bf16x8*)&kvb[(wv * 16 + n16) * KSTR + quad * 8];
        const bf16x8 b1 = *(const bf16x8*)&kvb[(wv * 16 + n16) * KSTR + 32 + quad * 8];
        const int key_abs = kb + wv * 16 + n16;
        #pragma unroll
        for (int qt = 0; qt < 2; ++qt) {
            f32x4 acc = {0.f, 0.f, 0.f, 0.f};
            acc = __builtin_amdgcn_mfma_f32_16x16x32_bf16(aqf[qt][0], b0, acc, 0, 0, 0);
            acc = __builtin_amdgcn_mfma_f32_16x16x32_bf16(aqf[qt][1], b1, acc, 0, 0, 0);

            // D: col(lane&15)=key-in-tile, row=quad*4+reg=q row. No max-subtraction:
            // |scores| <~ 8 so exp() is safe in fp32 (ref's softmax shift cancels).
            #pragma unroll
            for (int r = 0; r < 4; ++r) {
                const int qrow  = qt * 16 + quad * 4 + r;
                const int q_abs = q0 + qrow;
                const bool in   = (key_abs < S_LEN) &&
                                  (key_abs >= q_abs - WIN) && (key_abs <= q_abs + WIN);
                const float e = in ? __expf(acc[r] * 0.125f) : 0.f;
                pbf[qrow * PBSTR + c * 64 + wv * 16 + n16] = f2bf(e);
                psum[qt * 4 + r] += e;
            }
        }
        __syncthreads();
    }

    // ---- prefetch V chunk 0 (hides under row-sum reduction) ----
    float4 vx0, vx1, vx2, vx3;
    {
        const int kg = min(k0 + skey, S_LEN - 1);
        const float4* s4 = (const float4*)(Vh + (size_t)kg * D_DIM + sd0);
        vx0 = s4[0]; vx1 = s4[1]; vx2 = s4[2]; vx3 = s4[3];
    }

    // ---- row sums -> linv ----
    #pragma unroll
    for (int i = 0; i < 8; ++i) {
        float s = psum[i];
        s += __shfl_down(s, 8, 16);
        s += __shfl_down(s, 4, 16);
        s += __shfl_down(s, 2, 16);
        s += __shfl_down(s, 1, 16);
        if (n16 == 0) red[wv * TQ + (i >> 2) * 16 + quad * 4 + (i & 3)] = s;
    }
    __syncthreads();
    if (tid < TQ)
        linv[tid] = 1.f / (red[tid] + red[TQ + tid] + red[2 * TQ + tid] + red[3 * TQ + tid]);
    __syncthreads();

    // ---------------- Pass 2: PV via MFMA (V transposed + XOR-swizzled in LDS) ----------------
    f32x4 oacc0 = {0.f, 0.f, 0.f, 0.f};
    f32x4 oacc1 = {0.f, 0.f, 0.f, 0.f};
    const int dd = wv * 16 + n16;                       // this lane's output d
    const int sd = ((dd >> 4) + (dd & 7)) & 7;          // read-side swizzle
    #pragma unroll
    for (int c = 0; c < NCH; ++c) {
        {   // stage V chunk transposed from regs: Vt[d][key^8*s(d)] bf16, stride 64
            const float vals[16] = {vx0.x,vx0.y,vx0.z,vx0.w, vx1.x,vx1.y,vx1.z,vx1.w,
                                    vx2.x,vx2.y,vx2.z,vx2.w, vx3.x,vx3.y,vx3.z,vx3.w};
            #pragma unroll
            for (int jj = 0; jj < 16; ++jj) {
                const int d  = sd0 + jj;
                const int sw = ((d >> 4) + (d & 7)) & 7;
                kvb[d * 64 + (skey ^ (sw * 8))] = f2bf(vals[jj]);
            }
        }
        __syncthreads();

        ZEROS(9 + c);   // overlap remaining zero rows with PV phases

        // issue next chunk's V loads; latency hides under PV MFMAs below
        if (c + 1 < NCH) {
            const int kg = min(k0 + (c + 1) * 64 + skey, S_LEN - 1);
            const float4* s4 = (const float4*)(Vh + (size_t)kg * D_DIM + sd0);
            vx0 = s4[0]; vx1 = s4[1]; vx2 = s4[2]; vx3 = s4[3];
        }

        // B = Vt[k=key][n=d] shared across both q-tiles; A = P[m=q][k=key] from pbf
        const bf16x8 vb0 = *(const bf16x8*)&kvb[dd * 64 + 8 * (quad ^ sd)];
        const bf16x8 vb1 = *(const bf16x8*)&kvb[dd * 64 + 8 * ((4 + quad) ^ sd)];
        const bf16x8 pa00 = *(const bf16x8*)&pbf[n16 * PBSTR + c * 64 + quad * 8];
        const bf16x8 pa01 = *(const bf16x8*)&pbf[n16 * PBSTR + c * 64 + 32 + quad * 8];
        const bf16x8 pa10 = *(const bf16x8*)&pbf[(16 + n16) * PBSTR + c * 64 + quad * 8];
        const bf16x8 pa11 = *(const bf16x8*)&pbf[(16 + n16) * PBSTR + c * 64 + 32 + quad * 8];
        oacc0 = __builtin_amdgcn_mfma_f32_16x16x32_bf16(pa00, vb0, oacc0, 0, 0, 0);
        oacc0 = __builtin_amdgcn_mfma_f32_16x16x32_bf16(pa01, vb1, oacc0, 0, 0, 0);
        oacc1 = __builtin_amdgcn_mfma_f32_16x16x32_bf16(pa10, vb0, oacc1, 0, 0, 0);
        oacc1 = __builtin_amdgcn_mfma_f32_16x16x32_bf16(pa11, vb1, oacc1, 0, 0, 0);
        __syncthreads();
    }
    #pragma unroll
    for (int r = 0; r < 4; ++r) {
        const int qr = quad * 4 + r;
        out[((size_t)h * S_LEN + q0 + qr) * D_DIM + dd]      = oacc0[r] * linv[qr];
        out[((size_t)h * S_LEN + q0 + 16 + qr) * D_DIM + dd] = oacc1[r] * linv[16 + qr];
    }

    // ---------------- attn band span only: [k0, k0+576) per row (zeros already written) ----------------
    // 32 rows x 144 f32x4 = 4608 stores / 256 threads = 18 per thread.
    for (int i = tid; i < TQ * 144; i += 256) {
        const int qq   = i / 144;                 // constant division -> magic mul
        const int c4   = i - qq * 144;
        const int col4 = l4 + c4;
        if (col4 < 1024) {
            const int qa  = q0 + qq;
            const int b0q = max(qa - WIN, 0);
            const int b1q = min(qa + WIN, S_LEN - 1);
            const float qi = linv[qq];
            const unsigned short* prow = &pbf[qq * PBSTR];
            const int j = col4 * 4;
            f32x4 w = {0.f, 0.f, 0.f, 0.f};
            if (j >= b0q && j + 3 <= b1q) {
                const u16x4 p = *(const u16x4*)&prow[j - k0];
                w[0] = bf2f(p.x) * qi; w[1] = bf2f(p.y) * qi;
                w[2] = bf2f(p.z) * qi; w[3] = bf2f(p.w) * qi;
            } else if (j + 3 >= b0q && j <= b1q) {
                #pragma unroll
                for (int e = 0; e < 4; ++e) {
                    const int jj = j + e;
                    if (jj >= b0q && jj <= b1q) w[e] = bf2f(prow[jj - k0]) * qi;
                }
            }
            f32x4* arow = (f32x4*)(attn + ((size_t)h * S_LEN + qa) * S_LEN);
            __builtin_nontemporal_store(w, &arow[col4]);
        }
    }
#undef ZEROS
}

extern "C" void kernel_launch(void* const* d_in, const int* in_sizes, int n_in,
                              void* d_out, int out_size, void* d_ws, size_t ws_size,
                              hipStream_t stream) {
    const float* Q = (const float*)d_in[0];
    const float* K = (const float*)d_in[1];
    const float* V = (const float*)d_in[2];
    float* out  = (float*)d_out;
    float* attn = out + (size_t)H_NUM * S_LEN * D_DIM;

    dim3 grid(S_LEN / TQ, H_NUM);
    swa_kernel<<<grid, 256, 0, stream>>>(Q, K, V, out, attn);
}